// Round 1
// 699.949 us; speedup vs baseline: 1.0370x; 1.0370x over previous
//
#include <hip/hip_runtime.h>
#include <hip/hip_bf16.h>

#define NN 50000
#define NE 600000
#define DIM 128
#define NG 64
#define NCHUNK 98           // ceil(50000/512)

using bf16x8 = __attribute__((ext_vector_type(8))) __bf16;
using bf16x4 = __attribute__((ext_vector_type(4))) __bf16;
using f32x4  = __attribute__((ext_vector_type(4))) float;

// convert 8 contiguous fp32 -> bf16x8
__device__ __forceinline__ bf16x8 cvt8(const float* __restrict__ p) {
    f32x4 a = *(const f32x4*)p;
    f32x4 b = *(const f32x4*)(p + 4);
    bf16x8 r;
    #pragma unroll
    for (int i = 0; i < 4; ++i) { r[i] = (__bf16)a[i]; r[i + 4] = (__bf16)b[i]; }
    return r;
}

// Stage W[128][128] fp32 -> bf16 LDS, 136-elem row stride (no 4+-way conflicts)
__device__ __forceinline__ void stage_weights(const float* __restrict__ W, __bf16* sW) {
    for (int i = threadIdx.x; i < 128 * 16; i += 256) {
        int row = i >> 4, seg = i & 15;
        *(bf16x8*)(&sW[row * 136 + seg * 8]) = cvt8(W + row * 128 + seg * 8);
    }
    __syncthreads();
}

// ---------------------------------------------------------------------------
// H = node_h @ w1^T + b1  (fp32 in/out, bf16 MFMA core)
// OPERAND-SWAPPED: A = W-tile, B = X rows  =>  C row = out-dim, C col = node.
// Each lane then owns 4-dim contiguous f32x4 chunks of ONE node -> 16B stores.
// ---------------------------------------------------------------------------
__global__ __launch_bounds__(256) void gemm_bias(
    const float* __restrict__ X, const float* __restrict__ W,
    const float* __restrict__ bias, float* __restrict__ Y, int M)
{
    __shared__ __bf16 sW[128 * 136];
    stage_weights(W, sW);

    int wave = threadIdx.x >> 6, lane = threadIdx.x & 63;
    int col = lane & 15, quad = lane >> 4;
    int tile = (blockIdx.x * 4 + wave) * 16;
    if (tile >= M) return;

    f32x4 acc[8] = {};
    const float* xp = X + (size_t)(tile + col) * DIM + quad * 8;
    #pragma unroll
    for (int k0 = 0; k0 < 128; k0 += 32) {
        bf16x8 b = cvt8(xp + k0);                 // B[k][col=node]
        #pragma unroll
        for (int t = 0; t < 8; ++t) {
            bf16x8 a = *(const bf16x8*)(&sW[(t * 16 + col) * 136 + k0 + quad * 8]); // A[row=dim][k]
            acc[t] = __builtin_amdgcn_mfma_f32_16x16x32_bf16(a, b, acc[t], 0, 0, 0);
        }
    }
    // acc[t][r] = Y[node = tile+col][dim = t*16 + quad*4 + r]
    float* yp = Y + (size_t)(tile + col) * DIM + quad * 4;
    #pragma unroll
    for (int t = 0; t < 8; ++t) {
        f32x4 bv = *(const f32x4*)(bias + t * 16 + quad * 4);
        f32x4 o;
        #pragma unroll
        for (int r = 0; r < 4; ++r) o[r] = acc[t][r] + bv[r];
        *(f32x4*)(yp + t * 16) = o;
    }
}

// ===========================================================================
// CSR build: histogram -> 3-stage exclusive scan -> slot assignment
// ===========================================================================
__global__ __launch_bounds__(256) void k_hist(const int* __restrict__ dst, int* __restrict__ deg) {
    int e = blockIdx.x * 256 + threadIdx.x;
    if (e < NE) atomicAdd(&deg[dst[e]], 1);
}

__global__ __launch_bounds__(256) void k_scan_a(const int* __restrict__ deg, int* __restrict__ chunkSum) {
    __shared__ int s[256];
    int c = blockIdx.x, t = threadIdx.x;
    int b = c * 512 + t;
    int v = (b < NN) ? deg[b] : 0;
    if (b + 256 < NN) v += deg[b + 256];
    s[t] = v; __syncthreads();
    for (int off = 128; off > 0; off >>= 1) {
        if (t < off) s[t] += s[t + off];
        __syncthreads();
    }
    if (t == 0) chunkSum[c] = s[0];
}

__global__ __launch_bounds__(128) void k_scan_b(const int* __restrict__ chunkSum,
                                                int* __restrict__ chunkOff, int* __restrict__ rowptr) {
    __shared__ int s[128];
    int t = threadIdx.x;
    int v = (t < NCHUNK) ? chunkSum[t] : 0;
    s[t] = v; __syncthreads();
    for (int off = 1; off < 128; off <<= 1) {
        int x = (t >= off) ? s[t - off] : 0;
        __syncthreads();
        s[t] += x;
        __syncthreads();
    }
    chunkOff[t] = s[t] - v;           // exclusive
    if (t == 0) rowptr[NN] = NE;
}

__global__ __launch_bounds__(512) void k_scan_c(const int* __restrict__ deg,
                                                const int* __restrict__ chunkOff,
                                                int* __restrict__ rowptr, int* __restrict__ pos) {
    __shared__ int s[512];
    int c = blockIdx.x, t = threadIdx.x;
    int i = c * 512 + t;
    int v = (i < NN) ? deg[i] : 0;
    s[t] = v; __syncthreads();
    for (int off = 1; off < 512; off <<= 1) {
        int x = (t >= off) ? s[t - off] : 0;
        __syncthreads();
        s[t] += x;
        __syncthreads();
    }
    if (i < NN) { rowptr[i] = chunkOff[c] + s[t] - v; pos[i] = 0; }
}

__global__ __launch_bounds__(256) void k_slot(const int* __restrict__ dst,
                                              const int* __restrict__ rowptr,
                                              int* __restrict__ pos, int* __restrict__ slot) {
    int e = blockIdx.x * 256 + threadIdx.x;
    if (e >= NE) return;
    int d = dst[e];
    int p = atomicAdd(&pos[d], 1);
    slot[e] = rowptr[d] + p;
}

// ---------------------------------------------------------------------------
// Edge GEMM: msg = silu(h[src] + ea @ we^T + be), stored bf16 at dst-sorted
// slot. No atomics.
// OPERAND-SWAPPED: C col = edge, C row = dim. Each lane owns 32 dims of ONE
// edge -> H gather becomes f32x4 loads, MSG scatter becomes bf16x4 stores.
// ---------------------------------------------------------------------------
__global__ __launch_bounds__(256) void edge_msg_sorted(
    const float* __restrict__ EA, const float* __restrict__ W,
    const float* __restrict__ bias,
    const int* __restrict__ src, const int* __restrict__ slot,
    const float* __restrict__ H, __hip_bfloat16* __restrict__ MSG)
{
    __shared__ __bf16 sW[128 * 136];
    stage_weights(W, sW);

    int wave = threadIdx.x >> 6, lane = threadIdx.x & 63;
    int col = lane & 15, quad = lane >> 4;
    int tile = (blockIdx.x * 4 + wave) * 16;   // NE = 16*37500 = 4*9375*16: always full

    f32x4 acc[8] = {};
    const float* xp = EA + (size_t)(tile + col) * DIM + quad * 8;
    #pragma unroll
    for (int k0 = 0; k0 < 128; k0 += 32) {
        bf16x8 b = cvt8(xp + k0);                 // B[k][col=edge]
        #pragma unroll
        for (int t = 0; t < 8; ++t) {
            bf16x8 a = *(const bf16x8*)(&sW[(t * 16 + col) * 136 + k0 + quad * 8]); // A[row=dim][k]
            acc[t] = __builtin_amdgcn_mfma_f32_16x16x32_bf16(a, b, acc[t], 0, 0, 0);
        }
    }

    // acc[t][r] = msg-pre[edge = tile+col][dim = t*16 + quad*4 + r]
    int e  = tile + col;
    int s  = src[e];
    int sl = slot[e];
    const float* hp = H + (size_t)s * DIM + quad * 4;
    __hip_bfloat16* mp = MSG + (size_t)sl * DIM + quad * 4;
    #pragma unroll
    for (int t = 0; t < 8; ++t) {
        f32x4 bv = *(const f32x4*)(bias + t * 16 + quad * 4);
        f32x4 hv = *(const f32x4*)(hp + t * 16);
        bf16x4 o;
        #pragma unroll
        for (int r = 0; r < 4; ++r) {
            float v = acc[t][r] + bv[r] + hv[r];
            v = v / (1.f + __expf(-v));            // SiLU
            o[r] = (__bf16)v;
        }
        *(bf16x4*)(mp + t * 16) = o;
    }
}

// ---------------------------------------------------------------------------
// Per-node gather of contiguous msg slots + x = silu((1+eps)h + agg) + node_h
// (in-place over H). One 128-thread block per node, thread = dim.
// 4-deep unroll: independent loads in flight (latency hiding).
// ---------------------------------------------------------------------------
__global__ __launch_bounds__(128) void k_gather(
    const __hip_bfloat16* __restrict__ MSG, const int* __restrict__ rowptr,
    float* __restrict__ H, const float* __restrict__ node_h,
    const float* __restrict__ epsp)
{
    int n = blockIdx.x, d = threadIdx.x;
    int s = rowptr[n], epos = rowptr[n + 1];
    const __hip_bfloat16* mp = MSG + (size_t)s * DIM + d;
    float a0 = 0.f, a1 = 0.f, a2 = 0.f, a3 = 0.f;
    int e = s;
    for (; e + 4 <= epos; e += 4, mp += 4 * DIM) {
        a0 += __bfloat162float(mp[0]);
        a1 += __bfloat162float(mp[DIM]);
        a2 += __bfloat162float(mp[2 * DIM]);
        a3 += __bfloat162float(mp[3 * DIM]);
    }
    for (; e < epos; ++e, mp += DIM) a0 += __bfloat162float(mp[0]);
    float acc = (a0 + a1) + (a2 + a3);
    size_t idx = (size_t)n * DIM + d;
    float v = (1.f + epsp[0]) * H[idx] + acc;
    v = v / (1.f + __expf(-v));
    H[idx] = v + node_h[idx];
}

// ===========================================================================
// GraphNorm: single stats pass (sum + sumsq) -> finalize computes
// var = E[x^2] - mean^2 * ms * (2 - ms)   (eliminates the old var_pass).
// 16 nodes / 128-thread block; batch is sorted so runs are contiguous.
// ===========================================================================
__global__ __launch_bounds__(128) void stats_pass(
    const float* __restrict__ X, const int* __restrict__ batch,
    float* __restrict__ SUMS, float* __restrict__ SQS,
    float* __restrict__ CNT, int npb)
{
    int d = threadIdx.x;
    int n0 = blockIdx.x * npb;
    int nend = min(n0 + npb, NN);
    if (n0 >= NN) return;
    int cur_g = batch[n0];
    float run = 0.f, run2 = 0.f; int runlen = 0;
    for (int n = n0; n < nend; ++n) {
        int g = batch[n];
        if (g != cur_g) {
            atomicAdd(&SUMS[cur_g * DIM + d], run);
            atomicAdd(&SQS[cur_g * DIM + d], run2);
            if (d == 0) atomicAdd(&CNT[cur_g], (float)runlen);
            run = 0.f; run2 = 0.f; runlen = 0; cur_g = g;
        }
        float x = X[(size_t)n * DIM + d];
        run += x; run2 += x * x; runlen++;
    }
    atomicAdd(&SUMS[cur_g * DIM + d], run);
    atomicAdd(&SQS[cur_g * DIM + d], run2);
    if (d == 0) atomicAdd(&CNT[cur_g], (float)runlen);
}

__global__ __launch_bounds__(128) void finalize(
    const float* __restrict__ X, const int* __restrict__ batch,
    const float* __restrict__ msc,
    const float* __restrict__ SUMS, const float* __restrict__ SQS,
    const float* __restrict__ CNT,
    const float* __restrict__ gw, const float* __restrict__ gb,
    float* __restrict__ OUT, int npb)
{
    int d = threadIdx.x;
    int n0 = blockIdx.x * npb;
    int nend = min(n0 + npb, NN);
    if (n0 >= NN) return;
    float ms = msc[d], wd = gw[d], bd = gb[d];
    int cur_g = -1;
    float mean = 0.f, rstd = 0.f;
    for (int n = n0; n < nend; ++n) {
        int g = batch[n];
        if (g != cur_g) {
            cur_g = g;
            float c = fmaxf(CNT[g], 1.f);
            mean = SUMS[g * DIM + d] / c;
            float ex2 = SQS[g * DIM + d] / c;
            // var = E[(x - mean*ms)^2] = E[x^2] - mean^2 * ms * (2 - ms)
            float var = ex2 - mean * mean * ms * (2.f - ms);
            rstd = rsqrtf(fmaxf(var, 0.f) + 1e-5f);
        }
        size_t idx = (size_t)n * DIM + d;
        float v = X[idx] - mean * ms;
        OUT[idx] = wd * v * rstd + bd;
    }
}

// ===========================================================================
// Fallback path kernels (atomic scatter) if ws is too small
// ===========================================================================
__global__ __launch_bounds__(256) void edge_msg_atomic(
    const float* __restrict__ EA, const float* __restrict__ W,
    const float* __restrict__ bias,
    const int* __restrict__ src, const int* __restrict__ dst,
    const float* __restrict__ H, float* __restrict__ AGG)
{
    __shared__ __bf16 sW[128 * 136];
    stage_weights(W, sW);
    int wave = threadIdx.x >> 6, lane = threadIdx.x & 63;
    int col = lane & 15, quad = lane >> 4;
    int tile = (blockIdx.x * 4 + wave) * 16;
    f32x4 acc[8] = {};
    const float* xp = EA + (size_t)(tile + col) * DIM + quad * 8;
    #pragma unroll
    for (int k0 = 0; k0 < 128; k0 += 32) {
        bf16x8 b = cvt8(xp + k0);
        #pragma unroll
        for (int t = 0; t < 8; ++t) {
            bf16x8 a = *(const bf16x8*)(&sW[(t * 16 + col) * 136 + k0 + quad * 8]);
            acc[t] = __builtin_amdgcn_mfma_f32_16x16x32_bf16(a, b, acc[t], 0, 0, 0);
        }
    }
    int e = tile + col;
    int s = src[e], dd = dst[e];
    const float* hp = H + (size_t)s * DIM + quad * 4;
    float* ap = AGG + (size_t)dd * DIM + quad * 4;
    #pragma unroll
    for (int t = 0; t < 8; ++t) {
        f32x4 bv = *(const f32x4*)(bias + t * 16 + quad * 4);
        f32x4 hv = *(const f32x4*)(hp + t * 16);
        #pragma unroll
        for (int r = 0; r < 4; ++r) {
            float v = acc[t][r] + bv[r] + hv[r];
            v = v / (1.f + __expf(-v));
            atomicAdd(&ap[t * 16 + r], v);
        }
    }
}

__global__ __launch_bounds__(128) void fuse_x_atomic(
    float* __restrict__ H, const float* __restrict__ AGG,
    const float* __restrict__ node_h, const float* __restrict__ epsp, int npb)
{
    int d = threadIdx.x;
    int n0 = blockIdx.x * npb;
    int nend = min(n0 + npb, NN);
    if (n0 >= NN) return;
    float epsv = 1.f + epsp[0];
    for (int n = n0; n < nend; ++n) {
        size_t idx = (size_t)n * DIM + d;
        float v = epsv * H[idx] + AGG[idx];
        v = v / (1.f + __expf(-v));
        H[idx] = v + node_h[idx];
    }
}

// ===========================================================================
extern "C" void kernel_launch(void* const* d_in, const int* in_sizes, int n_in,
                              void* d_out, int out_size, void* d_ws, size_t ws_size,
                              hipStream_t stream) {
    const float* node_h    = (const float*)d_in[0];
    const float* edge_attr = (const float*)d_in[1];
    const int*   batch     = (const int*)d_in[2];
    const int*   eidx      = (const int*)d_in[3];   // [2][NE]: src, dst
    const float* w1        = (const float*)d_in[4];
    const float* b1        = (const float*)d_in[5];
    const float* we        = (const float*)d_in[6];
    const float* be        = (const float*)d_in[7];
    const float* eps       = (const float*)d_in[8];
    const float* gnw       = (const float*)d_in[9];
    const float* gnb       = (const float*)d_in[10];
    const float* gnms      = (const float*)d_in[11];
    const int* src = eidx, * dst = eidx + NE;

    char* base = (char*)d_ws;
    float* H = (float*)base;                                    // 25.6 MB

    // fast-path layout (bytes)
    size_t oMSG   = 25600000;                                   // bf16 [E][128] = 153.6 MB
    size_t oROW   = oMSG + 153600000;                           // int [NN+1]
    size_t oDEG   = oROW + 200064;                              // int [NN]   (also pos)
    size_t oSUMS  = oDEG + 200000;                              // f [G*D]
    size_t oSQS   = oSUMS + 32768;                              // f [G*D]
    size_t oCNT   = oSQS + 32768;
    size_t oSLOT  = oCNT + 256;                                 // int [NE]
    size_t oCSA   = oSLOT + 2400000;                            // chunkSum int[128]
    size_t oCSB   = oCSA + 512;                                 // chunkOff int[128]
    size_t needed = oCSB + 512;

    bool fast = ws_size >= needed;

    if (fast) {
        __hip_bfloat16* MSG = (__hip_bfloat16*)(base + oMSG);
        int* rowptr = (int*)(base + oROW);
        int* deg    = (int*)(base + oDEG);
        float* SUMS = (float*)(base + oSUMS);
        float* SQS  = (float*)(base + oSQS);
        float* CNT  = (float*)(base + oCNT);
        int* slot   = (int*)(base + oSLOT);
        int* csum   = (int*)(base + oCSA);
        int* coff   = (int*)(base + oCSB);

        // zero deg + SUMS + SQS + CNT (contiguous)
        hipMemsetAsync(deg, 0, 200000 + 32768 + 32768 + 256, stream);

        gemm_bias<<<782, 256, 0, stream>>>(node_h, w1, b1, H, NN);
        k_hist  <<<(NE + 255) / 256, 256, 0, stream>>>(dst, deg);
        k_scan_a<<<NCHUNK, 256, 0, stream>>>(deg, csum);
        k_scan_b<<<1, 128, 0, stream>>>(csum, coff, rowptr);
        k_scan_c<<<NCHUNK, 512, 0, stream>>>(deg, coff, rowptr, deg /*pos, zeroed in-kernel*/);
        k_slot  <<<(NE + 255) / 256, 256, 0, stream>>>(dst, rowptr, deg, slot);
        edge_msg_sorted<<<9375, 256, 0, stream>>>(edge_attr, we, be, src, slot, H, MSG);
        k_gather<<<NN, 128, 0, stream>>>(MSG, rowptr, H, node_h, eps);
        stats_pass<<<3125, 128, 0, stream>>>(H, batch, SUMS, SQS, CNT, 16);
        finalize  <<<3125, 128, 0, stream>>>(H, batch, gnms, SUMS, SQS, CNT, gnw, gnb,
                                             (float*)d_out, 16);
    } else {
        // fallback: atomic path (ws >= ~51.3 MB known to exist)
        float* AGG  = H + 6400000;
        float* SUMS = H + 12800000;
        float* SQS  = SUMS + NG * DIM;
        float* CNT  = SQS + NG * DIM;
        hipMemsetAsync(AGG, 0, (size_t)(6400000 + NG * DIM * 2 + NG) * sizeof(float), stream);
        gemm_bias<<<782, 256, 0, stream>>>(node_h, w1, b1, H, NN);
        edge_msg_atomic<<<9375, 256, 0, stream>>>(edge_attr, we, be, src, dst, H, AGG);
        fuse_x_atomic<<<3125, 128, 0, stream>>>(H, AGG, node_h, eps, 16);
        stats_pass<<<3125, 128, 0, stream>>>(H, batch, SUMS, SQS, CNT, 16);
        finalize  <<<3125, 128, 0, stream>>>(H, batch, gnms, SUMS, SQS, CNT, gnw, gnb,
                                             (float*)d_out, 16);
    }
}

// Round 2
// 695.893 us; speedup vs baseline: 1.0431x; 1.0058x over previous
//
#include <hip/hip_runtime.h>
#include <hip/hip_bf16.h>

#define NN 50000
#define NE 600000
#define DIM 128
#define NG 64
#define NCHUNK 98           // ceil(50000/512)

using bf16x8 = __attribute__((ext_vector_type(8))) __bf16;
using bf16x4 = __attribute__((ext_vector_type(4))) __bf16;
using f32x4  = __attribute__((ext_vector_type(4))) float;

// convert 8 contiguous fp32 -> bf16x8
__device__ __forceinline__ bf16x8 cvt8(const float* __restrict__ p) {
    f32x4 a = *(const f32x4*)p;
    f32x4 b = *(const f32x4*)(p + 4);
    bf16x8 r;
    #pragma unroll
    for (int i = 0; i < 4; ++i) { r[i] = (__bf16)a[i]; r[i + 4] = (__bf16)b[i]; }
    return r;
}

// Stage W[128][128] fp32 -> bf16 LDS, 136-elem row stride (no 4+-way conflicts)
__device__ __forceinline__ void stage_weights(const float* __restrict__ W, __bf16* sW) {
    for (int i = threadIdx.x; i < 128 * 16; i += 256) {
        int row = i >> 4, seg = i & 15;
        *(bf16x8*)(&sW[row * 136 + seg * 8]) = cvt8(W + row * 128 + seg * 8);
    }
    __syncthreads();
}

// ---------------------------------------------------------------------------
// H = node_h @ w1^T + b1  (fp32 in/out, bf16 MFMA core)
// OPERAND-SWAPPED: A = W-tile, B = X rows  =>  C row = out-dim, C col = node.
// ---------------------------------------------------------------------------
__global__ __launch_bounds__(256) void gemm_bias(
    const float* __restrict__ X, const float* __restrict__ W,
    const float* __restrict__ bias, float* __restrict__ Y, int M)
{
    __shared__ __bf16 sW[128 * 136];
    stage_weights(W, sW);

    int wave = threadIdx.x >> 6, lane = threadIdx.x & 63;
    int col = lane & 15, quad = lane >> 4;
    int tile = (blockIdx.x * 4 + wave) * 16;
    if (tile >= M) return;

    f32x4 acc[8] = {};
    const float* xp = X + (size_t)(tile + col) * DIM + quad * 8;
    #pragma unroll
    for (int k0 = 0; k0 < 128; k0 += 32) {
        bf16x8 b = cvt8(xp + k0);                 // B[k][col=node]
        #pragma unroll
        for (int t = 0; t < 8; ++t) {
            bf16x8 a = *(const bf16x8*)(&sW[(t * 16 + col) * 136 + k0 + quad * 8]); // A[row=dim][k]
            acc[t] = __builtin_amdgcn_mfma_f32_16x16x32_bf16(a, b, acc[t], 0, 0, 0);
        }
    }
    // acc[t][r] = Y[node = tile+col][dim = t*16 + quad*4 + r]
    float* yp = Y + (size_t)(tile + col) * DIM + quad * 4;
    #pragma unroll
    for (int t = 0; t < 8; ++t) {
        f32x4 bv = *(const f32x4*)(bias + t * 16 + quad * 4);
        f32x4 o;
        #pragma unroll
        for (int r = 0; r < 4; ++r) o[r] = acc[t][r] + bv[r];
        *(f32x4*)(yp + t * 16) = o;
    }
}

// ===========================================================================
// CSR build: histogram -> 3-stage exclusive scan -> slot assignment
// ===========================================================================
__global__ __launch_bounds__(256) void k_hist(const int* __restrict__ dst, int* __restrict__ deg) {
    int e = blockIdx.x * 256 + threadIdx.x;
    if (e < NE) atomicAdd(&deg[dst[e]], 1);
}

__global__ __launch_bounds__(256) void k_scan_a(const int* __restrict__ deg, int* __restrict__ chunkSum) {
    __shared__ int s[256];
    int c = blockIdx.x, t = threadIdx.x;
    int b = c * 512 + t;
    int v = (b < NN) ? deg[b] : 0;
    if (b + 256 < NN) v += deg[b + 256];
    s[t] = v; __syncthreads();
    for (int off = 128; off > 0; off >>= 1) {
        if (t < off) s[t] += s[t + off];
        __syncthreads();
    }
    if (t == 0) chunkSum[c] = s[0];
}

__global__ __launch_bounds__(128) void k_scan_b(const int* __restrict__ chunkSum,
                                                int* __restrict__ chunkOff, int* __restrict__ rowptr) {
    __shared__ int s[128];
    int t = threadIdx.x;
    int v = (t < NCHUNK) ? chunkSum[t] : 0;
    s[t] = v; __syncthreads();
    for (int off = 1; off < 128; off <<= 1) {
        int x = (t >= off) ? s[t - off] : 0;
        __syncthreads();
        s[t] += x;
        __syncthreads();
    }
    chunkOff[t] = s[t] - v;           // exclusive
    if (t == 0) rowptr[NN] = NE;
}

__global__ __launch_bounds__(512) void k_scan_c(const int* __restrict__ deg,
                                                const int* __restrict__ chunkOff,
                                                int* __restrict__ rowptr, int* __restrict__ pos) {
    __shared__ int s[512];
    int c = blockIdx.x, t = threadIdx.x;
    int i = c * 512 + t;
    int v = (i < NN) ? deg[i] : 0;
    s[t] = v; __syncthreads();
    for (int off = 1; off < 512; off <<= 1) {
        int x = (t >= off) ? s[t - off] : 0;
        __syncthreads();
        s[t] += x;
        __syncthreads();
    }
    if (i < NN) { rowptr[i] = chunkOff[c] + s[t] - v; pos[i] = 0; }
}

__global__ __launch_bounds__(256) void k_slot(const int* __restrict__ dst,
                                              const int* __restrict__ rowptr,
                                              int* __restrict__ pos, int* __restrict__ slot) {
    int e = blockIdx.x * 256 + threadIdx.x;
    if (e >= NE) return;
    int d = dst[e];
    int p = atomicAdd(&pos[d], 1);
    slot[e] = rowptr[d] + p;
}

// ---------------------------------------------------------------------------
// Edge GEMM: msg = silu(h[src] + ea @ we^T + be), stored bf16 at dst-sorted
// slot. No atomics.
// OPERAND-SWAPPED: C col = edge, C row = dim. Each lane owns 32 dims of ONE
// edge -> H gather is f32x4 loads, MSG scatter is bf16x4 stores.
// LATENCY HOIST: src/slot issued before weight staging; all 8 H-row f32x4
// loads issued before the MFMA K-loop (pinned by sched_barrier) so their
// L2/L3 latency hides under staging / MFMA work instead of stalling the
// epilogue (Round-1 regression root cause: epilogue MLP collapsed 4x).
// ---------------------------------------------------------------------------
__global__ __launch_bounds__(256) void edge_msg_sorted(
    const float* __restrict__ EA, const float* __restrict__ W,
    const float* __restrict__ bias,
    const int* __restrict__ src, const int* __restrict__ slot,
    const float* __restrict__ H, __hip_bfloat16* __restrict__ MSG)
{
    __shared__ __bf16 sW[128 * 136];

    int wave = threadIdx.x >> 6, lane = threadIdx.x & 63;
    int col = lane & 15, quad = lane >> 4;
    int tile = (blockIdx.x * 4 + wave) * 16;   // NE = 16*37500 = 4*9375*16: always full
    int e  = tile + col;

    // (1) issue index loads first; latency hides under weight staging
    int s  = src[e];
    int sl = slot[e];

    stage_weights(W, sW);

    // (2) issue the full H[src] row now; latency hides under the MFMA loop
    const float* hp = H + (size_t)s * DIM + quad * 4;
    f32x4 hv[8];
    #pragma unroll
    for (int t = 0; t < 8; ++t) hv[t] = *(const f32x4*)(hp + t * 16);
    __builtin_amdgcn_sched_barrier(0);   // pin: loads stay issued before the loop

    f32x4 acc[8] = {};
    const float* xp = EA + (size_t)e * DIM + quad * 8;
    #pragma unroll
    for (int k0 = 0; k0 < 128; k0 += 32) {
        bf16x8 b = cvt8(xp + k0);                 // B[k][col=edge]
        #pragma unroll
        for (int t = 0; t < 8; ++t) {
            bf16x8 a = *(const bf16x8*)(&sW[(t * 16 + col) * 136 + k0 + quad * 8]); // A[row=dim][k]
            acc[t] = __builtin_amdgcn_mfma_f32_16x16x32_bf16(a, b, acc[t], 0, 0, 0);
        }
    }

    // acc[t][r] = msg-pre[edge = e][dim = t*16 + quad*4 + r]
    __hip_bfloat16* mp = MSG + (size_t)sl * DIM + quad * 4;
    #pragma unroll
    for (int t = 0; t < 8; ++t) {
        f32x4 bv = *(const f32x4*)(bias + t * 16 + quad * 4);
        bf16x4 o;
        #pragma unroll
        for (int r = 0; r < 4; ++r) {
            float v = acc[t][r] + bv[r] + hv[t][r];
            v = v / (1.f + __expf(-v));            // SiLU
            o[r] = (__bf16)v;
        }
        *(bf16x4*)(mp + t * 16) = o;
    }
}

// ---------------------------------------------------------------------------
// Per-node gather of contiguous msg slots + x = silu((1+eps)h + agg) + node_h
// (in-place over H). One 128-thread block per node, thread = dim.
// 4-deep unroll: independent loads in flight (latency hiding).
// ---------------------------------------------------------------------------
__global__ __launch_bounds__(128) void k_gather(
    const __hip_bfloat16* __restrict__ MSG, const int* __restrict__ rowptr,
    float* __restrict__ H, const float* __restrict__ node_h,
    const float* __restrict__ epsp)
{
    int n = blockIdx.x, d = threadIdx.x;
    int s = rowptr[n], epos = rowptr[n + 1];
    const __hip_bfloat16* mp = MSG + (size_t)s * DIM + d;
    float a0 = 0.f, a1 = 0.f, a2 = 0.f, a3 = 0.f;
    int e = s;
    for (; e + 4 <= epos; e += 4, mp += 4 * DIM) {
        a0 += __bfloat162float(mp[0]);
        a1 += __bfloat162float(mp[DIM]);
        a2 += __bfloat162float(mp[2 * DIM]);
        a3 += __bfloat162float(mp[3 * DIM]);
    }
    for (; e < epos; ++e, mp += DIM) a0 += __bfloat162float(mp[0]);
    float acc = (a0 + a1) + (a2 + a3);
    size_t idx = (size_t)n * DIM + d;
    float v = (1.f + epsp[0]) * H[idx] + acc;
    v = v / (1.f + __expf(-v));
    H[idx] = v + node_h[idx];
}

// ===========================================================================
// GraphNorm: single stats pass (sum + sumsq) -> finalize computes
// var = E[x^2] - mean^2 * ms * (2 - ms)   (no separate var_pass).
// 16 nodes / 128-thread block; batch is sorted so runs are contiguous.
// ===========================================================================
__global__ __launch_bounds__(128) void stats_pass(
    const float* __restrict__ X, const int* __restrict__ batch,
    float* __restrict__ SUMS, float* __restrict__ SQS,
    float* __restrict__ CNT, int npb)
{
    int d = threadIdx.x;
    int n0 = blockIdx.x * npb;
    int nend = min(n0 + npb, NN);
    if (n0 >= NN) return;
    int cur_g = batch[n0];
    float run = 0.f, run2 = 0.f; int runlen = 0;
    for (int n = n0; n < nend; ++n) {
        int g = batch[n];
        if (g != cur_g) {
            atomicAdd(&SUMS[cur_g * DIM + d], run);
            atomicAdd(&SQS[cur_g * DIM + d], run2);
            if (d == 0) atomicAdd(&CNT[cur_g], (float)runlen);
            run = 0.f; run2 = 0.f; runlen = 0; cur_g = g;
        }
        float x = X[(size_t)n * DIM + d];
        run += x; run2 += x * x; runlen++;
    }
    atomicAdd(&SUMS[cur_g * DIM + d], run);
    atomicAdd(&SQS[cur_g * DIM + d], run2);
    if (d == 0) atomicAdd(&CNT[cur_g], (float)runlen);
}

__global__ __launch_bounds__(128) void finalize(
    const float* __restrict__ X, const int* __restrict__ batch,
    const float* __restrict__ msc,
    const float* __restrict__ SUMS, const float* __restrict__ SQS,
    const float* __restrict__ CNT,
    const float* __restrict__ gw, const float* __restrict__ gb,
    float* __restrict__ OUT, int npb)
{
    int d = threadIdx.x;
    int n0 = blockIdx.x * npb;
    int nend = min(n0 + npb, NN);
    if (n0 >= NN) return;
    float ms = msc[d], wd = gw[d], bd = gb[d];
    int cur_g = -1;
    float mean = 0.f, rstd = 0.f;
    for (int n = n0; n < nend; ++n) {
        int g = batch[n];
        if (g != cur_g) {
            cur_g = g;
            float c = fmaxf(CNT[g], 1.f);
            mean = SUMS[g * DIM + d] / c;
            float ex2 = SQS[g * DIM + d] / c;
            // var = E[(x - mean*ms)^2] = E[x^2] - mean^2 * ms * (2 - ms)
            float var = ex2 - mean * mean * ms * (2.f - ms);
            rstd = rsqrtf(fmaxf(var, 0.f) + 1e-5f);
        }
        size_t idx = (size_t)n * DIM + d;
        float v = X[idx] - mean * ms;
        OUT[idx] = wd * v * rstd + bd;
    }
}

// ===========================================================================
// Fallback path kernels (atomic scatter) if ws is too small
// ===========================================================================
__global__ __launch_bounds__(256) void edge_msg_atomic(
    const float* __restrict__ EA, const float* __restrict__ W,
    const float* __restrict__ bias,
    const int* __restrict__ src, const int* __restrict__ dst,
    const float* __restrict__ H, float* __restrict__ AGG)
{
    __shared__ __bf16 sW[128 * 136];
    int wave = threadIdx.x >> 6, lane = threadIdx.x & 63;
    int col = lane & 15, quad = lane >> 4;
    int tile = (blockIdx.x * 4 + wave) * 16;
    int e = tile + col;
    int s = src[e], dd = dst[e];

    stage_weights(W, sW);

    const float* hp = H + (size_t)s * DIM + quad * 4;
    f32x4 hv[8];
    #pragma unroll
    for (int t = 0; t < 8; ++t) hv[t] = *(const f32x4*)(hp + t * 16);
    __builtin_amdgcn_sched_barrier(0);

    f32x4 acc[8] = {};
    const float* xp = EA + (size_t)e * DIM + quad * 8;
    #pragma unroll
    for (int k0 = 0; k0 < 128; k0 += 32) {
        bf16x8 b = cvt8(xp + k0);
        #pragma unroll
        for (int t = 0; t < 8; ++t) {
            bf16x8 a = *(const bf16x8*)(&sW[(t * 16 + col) * 136 + k0 + quad * 8]);
            acc[t] = __builtin_amdgcn_mfma_f32_16x16x32_bf16(a, b, acc[t], 0, 0, 0);
        }
    }
    float* ap = AGG + (size_t)dd * DIM + quad * 4;
    #pragma unroll
    for (int t = 0; t < 8; ++t) {
        f32x4 bv = *(const f32x4*)(bias + t * 16 + quad * 4);
        #pragma unroll
        for (int r = 0; r < 4; ++r) {
            float v = acc[t][r] + bv[r] + hv[t][r];
            v = v / (1.f + __expf(-v));
            atomicAdd(&ap[t * 16 + r], v);
        }
    }
}

__global__ __launch_bounds__(128) void fuse_x_atomic(
    float* __restrict__ H, const float* __restrict__ AGG,
    const float* __restrict__ node_h, const float* __restrict__ epsp, int npb)
{
    int d = threadIdx.x;
    int n0 = blockIdx.x * npb;
    int nend = min(n0 + npb, NN);
    if (n0 >= NN) return;
    float epsv = 1.f + epsp[0];
    for (int n = n0; n < nend; ++n) {
        size_t idx = (size_t)n * DIM + d;
        float v = epsv * H[idx] + AGG[idx];
        v = v / (1.f + __expf(-v));
        H[idx] = v + node_h[idx];
    }
}

// ===========================================================================
extern "C" void kernel_launch(void* const* d_in, const int* in_sizes, int n_in,
                              void* d_out, int out_size, void* d_ws, size_t ws_size,
                              hipStream_t stream) {
    const float* node_h    = (const float*)d_in[0];
    const float* edge_attr = (const float*)d_in[1];
    const int*   batch     = (const int*)d_in[2];
    const int*   eidx      = (const int*)d_in[3];   // [2][NE]: src, dst
    const float* w1        = (const float*)d_in[4];
    const float* b1        = (const float*)d_in[5];
    const float* we        = (const float*)d_in[6];
    const float* be        = (const float*)d_in[7];
    const float* eps       = (const float*)d_in[8];
    const float* gnw       = (const float*)d_in[9];
    const float* gnb       = (const float*)d_in[10];
    const float* gnms      = (const float*)d_in[11];
    const int* src = eidx, * dst = eidx + NE;

    char* base = (char*)d_ws;
    float* H = (float*)base;                                    // 25.6 MB

    // fast-path layout (bytes)
    size_t oMSG   = 25600000;                                   // bf16 [E][128] = 153.6 MB
    size_t oROW   = oMSG + 153600000;                           // int [NN+1]
    size_t oDEG   = oROW + 200064;                              // int [NN]   (also pos)
    size_t oSUMS  = oDEG + 200000;                              // f [G*D]
    size_t oSQS   = oSUMS + 32768;                              // f [G*D]
    size_t oCNT   = oSQS + 32768;
    size_t oSLOT  = oCNT + 256;                                 // int [NE]
    size_t oCSA   = oSLOT + 2400000;                            // chunkSum int[128]
    size_t oCSB   = oCSA + 512;                                 // chunkOff int[128]
    size_t needed = oCSB + 512;

    bool fast = ws_size >= needed;

    if (fast) {
        __hip_bfloat16* MSG = (__hip_bfloat16*)(base + oMSG);
        int* rowptr = (int*)(base + oROW);
        int* deg    = (int*)(base + oDEG);
        float* SUMS = (float*)(base + oSUMS);
        float* SQS  = (float*)(base + oSQS);
        float* CNT  = (float*)(base + oCNT);
        int* slot   = (int*)(base + oSLOT);
        int* csum   = (int*)(base + oCSA);
        int* coff   = (int*)(base + oCSB);

        // zero deg + SUMS + SQS + CNT (contiguous)
        hipMemsetAsync(deg, 0, 200000 + 32768 + 32768 + 256, stream);

        gemm_bias<<<782, 256, 0, stream>>>(node_h, w1, b1, H, NN);
        k_hist  <<<(NE + 255) / 256, 256, 0, stream>>>(dst, deg);
        k_scan_a<<<NCHUNK, 256, 0, stream>>>(deg, csum);
        k_scan_b<<<1, 128, 0, stream>>>(csum, coff, rowptr);
        k_scan_c<<<NCHUNK, 512, 0, stream>>>(deg, coff, rowptr, deg /*pos, zeroed in-kernel*/);
        k_slot  <<<(NE + 255) / 256, 256, 0, stream>>>(dst, rowptr, deg, slot);
        edge_msg_sorted<<<9375, 256, 0, stream>>>(edge_attr, we, be, src, slot, H, MSG);
        k_gather<<<NN, 128, 0, stream>>>(MSG, rowptr, H, node_h, eps);
        stats_pass<<<3125, 128, 0, stream>>>(H, batch, SUMS, SQS, CNT, 16);
        finalize  <<<3125, 128, 0, stream>>>(H, batch, gnms, SUMS, SQS, CNT, gnw, gnb,
                                             (float*)d_out, 16);
    } else {
        // fallback: atomic path (ws >= ~51.3 MB known to exist)
        float* AGG  = H + 6400000;
        float* SUMS = H + 12800000;
        float* SQS  = SUMS + NG * DIM;
        float* CNT  = SQS + NG * DIM;
        hipMemsetAsync(AGG, 0, (size_t)(6400000 + NG * DIM * 2 + NG) * sizeof(float), stream);
        gemm_bias<<<782, 256, 0, stream>>>(node_h, w1, b1, H, NN);
        edge_msg_atomic<<<9375, 256, 0, stream>>>(edge_attr, we, be, src, dst, H, AGG);
        fuse_x_atomic<<<3125, 128, 0, stream>>>(H, AGG, node_h, eps, 16);
        stats_pass<<<3125, 128, 0, stream>>>(H, batch, SUMS, SQS, CNT, 16);
        finalize  <<<3125, 128, 0, stream>>>(H, batch, gnms, SUMS, SQS, CNT, gnw, gnb,
                                             (float*)d_out, 16);
    }
}

// Round 3
// 681.998 us; speedup vs baseline: 1.0643x; 1.0204x over previous
//
#include <hip/hip_runtime.h>
#include <hip/hip_bf16.h>

#define NN 50000
#define NE 600000
#define DIM 128
#define NG 64
#define NCHUNK 98           // ceil(50000/512)

using bf16x8 = __attribute__((ext_vector_type(8))) __bf16;
using bf16x4 = __attribute__((ext_vector_type(4))) __bf16;
using f32x4  = __attribute__((ext_vector_type(4))) float;

// convert 8 contiguous fp32 -> bf16x8
__device__ __forceinline__ bf16x8 cvt8(const float* __restrict__ p) {
    f32x4 a = *(const f32x4*)p;
    f32x4 b = *(const f32x4*)(p + 4);
    bf16x8 r;
    #pragma unroll
    for (int i = 0; i < 4; ++i) { r[i] = (__bf16)a[i]; r[i + 4] = (__bf16)b[i]; }
    return r;
}

// Stage W[128][128] fp32 -> bf16 LDS, XOR chunk swizzle (no padding, 32 KB):
// 16B chunk seg of row r stored at chunk (seg ^ (r&15)).  Read side uses
// row&15 == col, so the column-slice read spreads over all 16 chunk slots.
template<int NT>
__device__ __forceinline__ void stage_weights_swz(const float* __restrict__ W, __bf16* sW) {
    for (int i = threadIdx.x; i < 128 * 16; i += NT) {
        int row = i >> 4, seg = i & 15;
        *(bf16x8*)(&sW[row * 128 + ((seg ^ (row & 15)) << 3)]) = cvt8(W + row * 128 + seg * 8);
    }
    __syncthreads();
}

// swizzled A-fragment read: logical [row=t*16+col][k0 + quad*8 ..+7]
__device__ __forceinline__ bf16x8 ldsA(const __bf16* sW, int t, int col, int quad, int k0) {
    int chunk = ((k0 >> 3) + quad) ^ col;        // (row&15)==col
    return *(const bf16x8*)(&sW[(t * 16 + col) * 128 + (chunk << 3)]);
}

// ---------------------------------------------------------------------------
// H = node_h @ w1^T + b1  (fp32 in/out, bf16 MFMA core)
// OPERAND-SWAPPED: A = W-tile, B = X rows  =>  C row = out-dim, C col = node.
// 512 threads / 8 waves share one 32 KB sW -> up to 32 waves/CU.
// ---------------------------------------------------------------------------
__global__ __launch_bounds__(512) void gemm_bias(
    const float* __restrict__ X, const float* __restrict__ W,
    const float* __restrict__ bias, float* __restrict__ Y, int M)
{
    __shared__ __bf16 sW[128 * 128];
    stage_weights_swz<512>(W, sW);

    int wave = threadIdx.x >> 6, lane = threadIdx.x & 63;
    int col = lane & 15, quad = lane >> 4;
    int tile = (blockIdx.x * 8 + wave) * 16;
    if (tile >= M) return;                        // after barrier: safe

    f32x4 acc[8] = {};
    const float* xp = X + (size_t)(tile + col) * DIM + quad * 8;
    #pragma unroll
    for (int k0 = 0; k0 < 128; k0 += 32) {
        bf16x8 b = cvt8(xp + k0);                 // B[k][col=node]
        #pragma unroll
        for (int t = 0; t < 8; ++t) {
            bf16x8 a = ldsA(sW, t, col, quad, k0); // A[row=dim][k]
            acc[t] = __builtin_amdgcn_mfma_f32_16x16x32_bf16(a, b, acc[t], 0, 0, 0);
        }
    }
    // acc[t][r] = Y[node = tile+col][dim = t*16 + quad*4 + r]
    float* yp = Y + (size_t)(tile + col) * DIM + quad * 4;
    #pragma unroll
    for (int t = 0; t < 8; ++t) {
        f32x4 bv = *(const f32x4*)(bias + t * 16 + quad * 4);
        f32x4 o;
        #pragma unroll
        for (int r = 0; r < 4; ++r) o[r] = acc[t][r] + bv[r];
        *(f32x4*)(yp + t * 16) = o;
    }
}

// ===========================================================================
// CSR build: histogram -> 3-stage exclusive scan -> slot assignment
// ===========================================================================
__global__ __launch_bounds__(256) void k_hist(const int* __restrict__ dst, int* __restrict__ deg) {
    int e = blockIdx.x * 256 + threadIdx.x;
    if (e < NE) atomicAdd(&deg[dst[e]], 1);
}

__global__ __launch_bounds__(256) void k_scan_a(const int* __restrict__ deg, int* __restrict__ chunkSum) {
    __shared__ int s[256];
    int c = blockIdx.x, t = threadIdx.x;
    int b = c * 512 + t;
    int v = (b < NN) ? deg[b] : 0;
    if (b + 256 < NN) v += deg[b + 256];
    s[t] = v; __syncthreads();
    for (int off = 128; off > 0; off >>= 1) {
        if (t < off) s[t] += s[t + off];
        __syncthreads();
    }
    if (t == 0) chunkSum[c] = s[0];
}

__global__ __launch_bounds__(128) void k_scan_b(const int* __restrict__ chunkSum,
                                                int* __restrict__ chunkOff, int* __restrict__ rowptr) {
    __shared__ int s[128];
    int t = threadIdx.x;
    int v = (t < NCHUNK) ? chunkSum[t] : 0;
    s[t] = v; __syncthreads();
    for (int off = 1; off < 128; off <<= 1) {
        int x = (t >= off) ? s[t - off] : 0;
        __syncthreads();
        s[t] += x;
        __syncthreads();
    }
    chunkOff[t] = s[t] - v;           // exclusive
    if (t == 0) rowptr[NN] = NE;
}

__global__ __launch_bounds__(512) void k_scan_c(const int* __restrict__ deg,
                                                const int* __restrict__ chunkOff,
                                                int* __restrict__ rowptr, int* __restrict__ pos) {
    __shared__ int s[512];
    int c = blockIdx.x, t = threadIdx.x;
    int i = c * 512 + t;
    int v = (i < NN) ? deg[i] : 0;
    s[t] = v; __syncthreads();
    for (int off = 1; off < 512; off <<= 1) {
        int x = (t >= off) ? s[t - off] : 0;
        __syncthreads();
        s[t] += x;
        __syncthreads();
    }
    if (i < NN) { rowptr[i] = chunkOff[c] + s[t] - v; pos[i] = 0; }
}

__global__ __launch_bounds__(256) void k_slot(const int* __restrict__ dst,
                                              const int* __restrict__ rowptr,
                                              int* __restrict__ pos, int* __restrict__ slot) {
    int e = blockIdx.x * 256 + threadIdx.x;
    if (e >= NE) return;
    int d = dst[e];
    int p = atomicAdd(&pos[d], 1);
    slot[e] = rowptr[d] + p;
}

// ---------------------------------------------------------------------------
// Edge GEMM: msg = silu(h[src] + ea @ we^T + be), stored bf16 at dst-sorted
// slot. No atomics.
// OPERAND-SWAPPED: C col = edge, C row = dim -> lane owns 32 dims of ONE edge.
// 512 threads / 8 waves / 32 KB swizzled sW; occupancy is the lever
// (round-2 lesson: 2.5 waves/SIMD cannot hide scatter latency).
// ---------------------------------------------------------------------------
__global__ __launch_bounds__(512) void edge_msg_sorted(
    const float* __restrict__ EA, const float* __restrict__ W,
    const float* __restrict__ bias,
    const int* __restrict__ src, const int* __restrict__ slot,
    const float* __restrict__ H, __hip_bfloat16* __restrict__ MSG)
{
    __shared__ __bf16 sW[128 * 128];

    int wave = threadIdx.x >> 6, lane = threadIdx.x & 63;
    int col = lane & 15, quad = lane >> 4;
    int tile = (blockIdx.x * 8 + wave) * 16;
    bool active = (tile < NE);
    int e  = active ? (tile + col) : 0;

    // index loads issued before staging; latency hides under it
    int s  = src[e];
    int sl = slot[e];

    stage_weights_swz<512>(W, sW);
    if (!active) return;                          // after barrier: safe

    f32x4 acc[8] = {};
    const float* xp = EA + (size_t)e * DIM + quad * 8;
    #pragma unroll
    for (int k0 = 0; k0 < 128; k0 += 32) {
        bf16x8 b = cvt8(xp + k0);                 // B[k][col=edge]
        #pragma unroll
        for (int t = 0; t < 8; ++t) {
            bf16x8 a = ldsA(sW, t, col, quad, k0); // A[row=dim][k]
            acc[t] = __builtin_amdgcn_mfma_f32_16x16x32_bf16(a, b, acc[t], 0, 0, 0);
        }
    }

    // epilogue: batch all 8 H loads (8 in flight), then compute + store
    const float* hp = H + (size_t)s * DIM + quad * 4;
    f32x4 hv[8];
    #pragma unroll
    for (int t = 0; t < 8; ++t) hv[t] = *(const f32x4*)(hp + t * 16);

    __hip_bfloat16* mp = MSG + (size_t)sl * DIM + quad * 4;
    #pragma unroll
    for (int t = 0; t < 8; ++t) {
        f32x4 bv = *(const f32x4*)(bias + t * 16 + quad * 4);
        bf16x4 o;
        #pragma unroll
        for (int r = 0; r < 4; ++r) {
            float v = acc[t][r] + bv[r] + hv[t][r];
            v = v / (1.f + __expf(-v));            // SiLU
            o[r] = (__bf16)v;
        }
        *(bf16x4*)(mp + t * 16) = o;
    }
}

// ---------------------------------------------------------------------------
// Per-node gather of contiguous msg slots + x = silu((1+eps)h + agg) + node_h
// (in-place over H). One 128-thread block per node, thread = dim.
// ---------------------------------------------------------------------------
__global__ __launch_bounds__(128) void k_gather(
    const __hip_bfloat16* __restrict__ MSG, const int* __restrict__ rowptr,
    float* __restrict__ H, const float* __restrict__ node_h,
    const float* __restrict__ epsp)
{
    int n = blockIdx.x, d = threadIdx.x;
    int s = rowptr[n], epos = rowptr[n + 1];
    const __hip_bfloat16* mp = MSG + (size_t)s * DIM + d;
    float a0 = 0.f, a1 = 0.f, a2 = 0.f, a3 = 0.f;
    int e = s;
    for (; e + 4 <= epos; e += 4, mp += 4 * DIM) {
        a0 += __bfloat162float(mp[0]);
        a1 += __bfloat162float(mp[DIM]);
        a2 += __bfloat162float(mp[2 * DIM]);
        a3 += __bfloat162float(mp[3 * DIM]);
    }
    for (; e < epos; ++e, mp += DIM) a0 += __bfloat162float(mp[0]);
    float acc = (a0 + a1) + (a2 + a3);
    size_t idx = (size_t)n * DIM + d;
    float v = (1.f + epsp[0]) * H[idx] + acc;
    v = v / (1.f + __expf(-v));
    H[idx] = v + node_h[idx];
}

// ===========================================================================
// GraphNorm: single stats pass (sum + sumsq) -> finalize computes
// var = E[x^2] - mean^2 * ms * (2 - ms).
// ===========================================================================
__global__ __launch_bounds__(128) void stats_pass(
    const float* __restrict__ X, const int* __restrict__ batch,
    float* __restrict__ SUMS, float* __restrict__ SQS,
    float* __restrict__ CNT, int npb)
{
    int d = threadIdx.x;
    int n0 = blockIdx.x * npb;
    int nend = min(n0 + npb, NN);
    if (n0 >= NN) return;
    int cur_g = batch[n0];
    float run = 0.f, run2 = 0.f; int runlen = 0;
    for (int n = n0; n < nend; ++n) {
        int g = batch[n];
        if (g != cur_g) {
            atomicAdd(&SUMS[cur_g * DIM + d], run);
            atomicAdd(&SQS[cur_g * DIM + d], run2);
            if (d == 0) atomicAdd(&CNT[cur_g], (float)runlen);
            run = 0.f; run2 = 0.f; runlen = 0; cur_g = g;
        }
        float x = X[(size_t)n * DIM + d];
        run += x; run2 += x * x; runlen++;
    }
    atomicAdd(&SUMS[cur_g * DIM + d], run);
    atomicAdd(&SQS[cur_g * DIM + d], run2);
    if (d == 0) atomicAdd(&CNT[cur_g], (float)runlen);
}

__global__ __launch_bounds__(128) void finalize(
    const float* __restrict__ X, const int* __restrict__ batch,
    const float* __restrict__ msc,
    const float* __restrict__ SUMS, const float* __restrict__ SQS,
    const float* __restrict__ CNT,
    const float* __restrict__ gw, const float* __restrict__ gb,
    float* __restrict__ OUT, int npb)
{
    int d = threadIdx.x;
    int n0 = blockIdx.x * npb;
    int nend = min(n0 + npb, NN);
    if (n0 >= NN) return;
    float ms = msc[d], wd = gw[d], bd = gb[d];
    int cur_g = -1;
    float mean = 0.f, rstd = 0.f;
    for (int n = n0; n < nend; ++n) {
        int g = batch[n];
        if (g != cur_g) {
            cur_g = g;
            float c = fmaxf(CNT[g], 1.f);
            mean = SUMS[g * DIM + d] / c;
            float ex2 = SQS[g * DIM + d] / c;
            float var = ex2 - mean * mean * ms * (2.f - ms);
            rstd = rsqrtf(fmaxf(var, 0.f) + 1e-5f);
        }
        size_t idx = (size_t)n * DIM + d;
        float v = X[idx] - mean * ms;
        OUT[idx] = wd * v * rstd + bd;
    }
}

// ===========================================================================
// Fallback path kernels (atomic scatter) if ws is too small
// ===========================================================================
__global__ __launch_bounds__(512) void edge_msg_atomic(
    const float* __restrict__ EA, const float* __restrict__ W,
    const float* __restrict__ bias,
    const int* __restrict__ src, const int* __restrict__ dst,
    const float* __restrict__ H, float* __restrict__ AGG)
{
    __shared__ __bf16 sW[128 * 128];
    int wave = threadIdx.x >> 6, lane = threadIdx.x & 63;
    int col = lane & 15, quad = lane >> 4;
    int tile = (blockIdx.x * 8 + wave) * 16;
    bool active = (tile < NE);
    int e = active ? (tile + col) : 0;
    int s = src[e], dd = dst[e];

    stage_weights_swz<512>(W, sW);
    if (!active) return;

    f32x4 acc[8] = {};
    const float* xp = EA + (size_t)e * DIM + quad * 8;
    #pragma unroll
    for (int k0 = 0; k0 < 128; k0 += 32) {
        bf16x8 b = cvt8(xp + k0);
        #pragma unroll
        for (int t = 0; t < 8; ++t) {
            bf16x8 a = ldsA(sW, t, col, quad, k0);
            acc[t] = __builtin_amdgcn_mfma_f32_16x16x32_bf16(a, b, acc[t], 0, 0, 0);
        }
    }
    const float* hp = H + (size_t)s * DIM + quad * 4;
    f32x4 hv[8];
    #pragma unroll
    for (int t = 0; t < 8; ++t) hv[t] = *(const f32x4*)(hp + t * 16);

    float* ap = AGG + (size_t)dd * DIM + quad * 4;
    #pragma unroll
    for (int t = 0; t < 8; ++t) {
        f32x4 bv = *(const f32x4*)(bias + t * 16 + quad * 4);
        #pragma unroll
        for (int r = 0; r < 4; ++r) {
            float v = acc[t][r] + bv[r] + hv[t][r];
            v = v / (1.f + __expf(-v));
            atomicAdd(&ap[t * 16 + r], v);
        }
    }
}

__global__ __launch_bounds__(128) void fuse_x_atomic(
    float* __restrict__ H, const float* __restrict__ AGG,
    const float* __restrict__ node_h, const float* __restrict__ epsp, int npb)
{
    int d = threadIdx.x;
    int n0 = blockIdx.x * npb;
    int nend = min(n0 + npb, NN);
    if (n0 >= NN) return;
    float epsv = 1.f + epsp[0];
    for (int n = n0; n < nend; ++n) {
        size_t idx = (size_t)n * DIM + d;
        float v = epsv * H[idx] + AGG[idx];
        v = v / (1.f + __expf(-v));
        H[idx] = v + node_h[idx];
    }
}

// ===========================================================================
extern "C" void kernel_launch(void* const* d_in, const int* in_sizes, int n_in,
                              void* d_out, int out_size, void* d_ws, size_t ws_size,
                              hipStream_t stream) {
    const float* node_h    = (const float*)d_in[0];
    const float* edge_attr = (const float*)d_in[1];
    const int*   batch     = (const int*)d_in[2];
    const int*   eidx      = (const int*)d_in[3];   // [2][NE]: src, dst
    const float* w1        = (const float*)d_in[4];
    const float* b1        = (const float*)d_in[5];
    const float* we        = (const float*)d_in[6];
    const float* be        = (const float*)d_in[7];
    const float* eps       = (const float*)d_in[8];
    const float* gnw       = (const float*)d_in[9];
    const float* gnb       = (const float*)d_in[10];
    const float* gnms      = (const float*)d_in[11];
    const int* src = eidx, * dst = eidx + NE;

    char* base = (char*)d_ws;
    float* H = (float*)base;                                    // 25.6 MB

    // fast-path layout (bytes)
    size_t oMSG   = 25600000;                                   // bf16 [E][128] = 153.6 MB
    size_t oROW   = oMSG + 153600000;                           // int [NN+1]
    size_t oDEG   = oROW + 200064;                              // int [NN]   (also pos)
    size_t oSUMS  = oDEG + 200000;                              // f [G*D]
    size_t oSQS   = oSUMS + 32768;                              // f [G*D]
    size_t oCNT   = oSQS + 32768;
    size_t oSLOT  = oCNT + 256;                                 // int [NE]
    size_t oCSA   = oSLOT + 2400000;                            // chunkSum int[128]
    size_t oCSB   = oCSA + 512;                                 // chunkOff int[128]
    size_t needed = oCSB + 512;

    bool fast = ws_size >= needed;

    if (fast) {
        __hip_bfloat16* MSG = (__hip_bfloat16*)(base + oMSG);
        int* rowptr = (int*)(base + oROW);
        int* deg    = (int*)(base + oDEG);
        float* SUMS = (float*)(base + oSUMS);
        float* SQS  = (float*)(base + oSQS);
        float* CNT  = (float*)(base + oCNT);
        int* slot   = (int*)(base + oSLOT);
        int* csum   = (int*)(base + oCSA);
        int* coff   = (int*)(base + oCSB);

        // zero deg + SUMS + SQS + CNT (contiguous)
        hipMemsetAsync(deg, 0, 200000 + 32768 + 32768 + 256, stream);

        gemm_bias<<<391, 512, 0, stream>>>(node_h, w1, b1, H, NN);
        k_hist  <<<(NE + 255) / 256, 256, 0, stream>>>(dst, deg);
        k_scan_a<<<NCHUNK, 256, 0, stream>>>(deg, csum);
        k_scan_b<<<1, 128, 0, stream>>>(csum, coff, rowptr);
        k_scan_c<<<NCHUNK, 512, 0, stream>>>(deg, coff, rowptr, deg /*pos, zeroed in-kernel*/);
        k_slot  <<<(NE + 255) / 256, 256, 0, stream>>>(dst, rowptr, deg, slot);
        edge_msg_sorted<<<4688, 512, 0, stream>>>(edge_attr, we, be, src, slot, H, MSG);
        k_gather<<<NN, 128, 0, stream>>>(MSG, rowptr, H, node_h, eps);
        stats_pass<<<3125, 128, 0, stream>>>(H, batch, SUMS, SQS, CNT, 16);
        finalize  <<<3125, 128, 0, stream>>>(H, batch, gnms, SUMS, SQS, CNT, gnw, gnb,
                                             (float*)d_out, 16);
    } else {
        // fallback: atomic path (ws >= ~51.3 MB known to exist)
        float* AGG  = H + 6400000;
        float* SUMS = H + 12800000;
        float* SQS  = SUMS + NG * DIM;
        float* CNT  = SQS + NG * DIM;
        hipMemsetAsync(AGG, 0, (size_t)(6400000 + NG * DIM * 2 + NG) * sizeof(float), stream);
        gemm_bias<<<391, 512, 0, stream>>>(node_h, w1, b1, H, NN);
        edge_msg_atomic<<<4688, 512, 0, stream>>>(edge_attr, we, be, src, dst, H, AGG);
        fuse_x_atomic<<<3125, 128, 0, stream>>>(H, AGG, node_h, eps, 16);
        stats_pass<<<3125, 128, 0, stream>>>(H, batch, SUMS, SQS, CNT, 16);
        finalize  <<<3125, 128, 0, stream>>>(H, batch, gnms, SUMS, SQS, CNT, gnw, gnb,
                                             (float*)d_out, 16);
    }
}

// Round 4
// 660.413 us; speedup vs baseline: 1.0991x; 1.0327x over previous
//
#include <hip/hip_runtime.h>
#include <hip/hip_bf16.h>

#define NN 50000
#define NE 600000
#define DIM 128
#define NG 64
#define NCHUNK 98           // ceil(50000/512)
#define NTILE_E 37500       // NE/16
#define EDGE_BLOCKS 1024    // persistent: 4 blocks/CU x 256 CU

using bf16x8 = __attribute__((ext_vector_type(8))) __bf16;
using bf16x4 = __attribute__((ext_vector_type(4))) __bf16;
using f32x4  = __attribute__((ext_vector_type(4))) float;

// convert 8 contiguous fp32 -> bf16x8
__device__ __forceinline__ bf16x8 cvt8(const float* __restrict__ p) {
    f32x4 a = *(const f32x4*)p;
    f32x4 b = *(const f32x4*)(p + 4);
    bf16x8 r;
    #pragma unroll
    for (int i = 0; i < 4; ++i) { r[i] = (__bf16)a[i]; r[i + 4] = (__bf16)b[i]; }
    return r;
}

// Stage W[128][128] fp32 -> bf16 LDS, XOR chunk swizzle (no padding, 32 KB):
// 16B chunk seg of row r stored at chunk (seg ^ (r&15)). Read side uses
// row&15 == col, so the column-slice read spreads over all 16 chunk slots.
template<int NT>
__device__ __forceinline__ void stage_weights_swz(const float* __restrict__ W, __bf16* sW) {
    for (int i = threadIdx.x; i < 128 * 16; i += NT) {
        int row = i >> 4, seg = i & 15;
        *(bf16x8*)(&sW[row * 128 + ((seg ^ (row & 15)) << 3)]) = cvt8(W + row * 128 + seg * 8);
    }
    __syncthreads();
}

// swizzled A-fragment read: logical [row=t*16+col][k0 + quad*8 ..+7]
__device__ __forceinline__ bf16x8 ldsA(const __bf16* sW, int t, int col, int quad, int k0) {
    int chunk = ((k0 >> 3) + quad) ^ col;        // (row&15)==col
    return *(const bf16x8*)(&sW[(t * 16 + col) * 128 + (chunk << 3)]);
}

// ---------------------------------------------------------------------------
// H = node_h @ w1^T + b1  (fp32 out + bf16 fragment-permuted copy Hb)
// OPERAND-SWAPPED: A = W-tile, B = X rows  =>  C row = out-dim, C col = node.
// Hb layout: dim' = quad*32 + t*4 + r  (matches MFMA C-fragment ownership),
// so the edge kernel gathers a src row as 4x contiguous 16B loads per lane.
// ---------------------------------------------------------------------------
__global__ __launch_bounds__(512) void gemm_bias(
    const float* __restrict__ X, const float* __restrict__ W,
    const float* __restrict__ bias, float* __restrict__ Y,
    __hip_bfloat16* __restrict__ Yb, int M)
{
    __shared__ __bf16 sW[128 * 128];
    stage_weights_swz<512>(W, sW);

    int wave = threadIdx.x >> 6, lane = threadIdx.x & 63;
    int col = lane & 15, quad = lane >> 4;
    int tile = (blockIdx.x * 8 + wave) * 16;
    if (tile >= M) return;                        // after barrier: safe

    f32x4 acc[8] = {};
    const float* xp = X + (size_t)(tile + col) * DIM + quad * 8;
    #pragma unroll
    for (int k0 = 0; k0 < 128; k0 += 32) {
        bf16x8 b = cvt8(xp + k0);                 // B[k][col=node]
        #pragma unroll
        for (int t = 0; t < 8; ++t) {
            bf16x8 a = ldsA(sW, t, col, quad, k0); // A[row=dim][k]
            acc[t] = __builtin_amdgcn_mfma_f32_16x16x32_bf16(a, b, acc[t], 0, 0, 0);
        }
    }
    // acc[t][r] = Y[node = tile+col][dim = t*16 + quad*4 + r]
    float* yp = Y + (size_t)(tile + col) * DIM + quad * 4;
    #pragma unroll
    for (int t = 0; t < 8; ++t) {
        f32x4 bv = *(const f32x4*)(bias + t * 16 + quad * 4);
        f32x4 o;
        #pragma unroll
        for (int r = 0; r < 4; ++r) o[r] = acc[t][r] + bv[r];
        *(f32x4*)(yp + t * 16) = o;
        #pragma unroll
        for (int r = 0; r < 4; ++r) acc[t][r] = o[r];  // keep biased value
    }
    if (Yb) {
        __hip_bfloat16* ybp = Yb + (size_t)(tile + col) * DIM + quad * 32;
        #pragma unroll
        for (int tp = 0; tp < 4; ++tp) {
            bf16x8 o8;
            #pragma unroll
            for (int r = 0; r < 4; ++r) {
                o8[r]     = (__bf16)acc[2 * tp][r];
                o8[4 + r] = (__bf16)acc[2 * tp + 1][r];
            }
            *(bf16x8*)(ybp + tp * 8) = o8;
        }
    }
}

// ===========================================================================
// CSR build: histogram -> 3-stage exclusive scan -> slot assignment
// ===========================================================================
__global__ __launch_bounds__(256) void k_hist(const int* __restrict__ dst, int* __restrict__ deg) {
    int e = blockIdx.x * 256 + threadIdx.x;
    if (e < NE) atomicAdd(&deg[dst[e]], 1);
}

__global__ __launch_bounds__(256) void k_scan_a(const int* __restrict__ deg, int* __restrict__ chunkSum) {
    __shared__ int s[256];
    int c = blockIdx.x, t = threadIdx.x;
    int b = c * 512 + t;
    int v = (b < NN) ? deg[b] : 0;
    if (b + 256 < NN) v += deg[b + 256];
    s[t] = v; __syncthreads();
    for (int off = 128; off > 0; off >>= 1) {
        if (t < off) s[t] += s[t + off];
        __syncthreads();
    }
    if (t == 0) chunkSum[c] = s[0];
}

__global__ __launch_bounds__(128) void k_scan_b(const int* __restrict__ chunkSum,
                                                int* __restrict__ chunkOff, int* __restrict__ rowptr) {
    __shared__ int s[128];
    int t = threadIdx.x;
    int v = (t < NCHUNK) ? chunkSum[t] : 0;
    s[t] = v; __syncthreads();
    for (int off = 1; off < 128; off <<= 1) {
        int x = (t >= off) ? s[t - off] : 0;
        __syncthreads();
        s[t] += x;
        __syncthreads();
    }
    chunkOff[t] = s[t] - v;           // exclusive
    if (t == 0) rowptr[NN] = NE;
}

__global__ __launch_bounds__(512) void k_scan_c(const int* __restrict__ deg,
                                                const int* __restrict__ chunkOff,
                                                int* __restrict__ rowptr, int* __restrict__ pos) {
    __shared__ int s[512];
    int c = blockIdx.x, t = threadIdx.x;
    int i = c * 512 + t;
    int v = (i < NN) ? deg[i] : 0;
    s[t] = v; __syncthreads();
    for (int off = 1; off < 512; off <<= 1) {
        int x = (t >= off) ? s[t - off] : 0;
        __syncthreads();
        s[t] += x;
        __syncthreads();
    }
    if (i < NN) { rowptr[i] = chunkOff[c] + s[t] - v; pos[i] = 0; }
}

__global__ __launch_bounds__(256) void k_slot(const int* __restrict__ dst,
                                              const int* __restrict__ rowptr,
                                              int* __restrict__ pos, int* __restrict__ slot) {
    int e = blockIdx.x * 256 + threadIdx.x;
    if (e >= NE) return;
    int d = dst[e];
    int p = atomicAdd(&pos[d], 1);
    slot[e] = rowptr[d] + p;
}

// ---------------------------------------------------------------------------
// Edge GEMM: msg = silu(h[src] + ea @ we^T + be), stored bf16 at dst-sorted
// slot. PERSISTENT: 1024 blocks stage W once, wave-stride over all tiles
// (round-3 lesson: per-block staging was 4.6x redundant; VMEM bytes/CU is
// the binding pipe -> Hb bf16 gather halves gather bytes).
// ---------------------------------------------------------------------------
__global__ __launch_bounds__(512) void edge_msg_sorted(
    const float* __restrict__ EA, const float* __restrict__ W,
    const float* __restrict__ bias,
    const int* __restrict__ src, const int* __restrict__ slot,
    const __hip_bfloat16* __restrict__ Hb, __hip_bfloat16* __restrict__ MSG)
{
    __shared__ __bf16 sW[128 * 128];
    stage_weights_swz<512>(W, sW);

    int wave = threadIdx.x >> 6, lane = threadIdx.x & 63;
    int col = lane & 15, quad = lane >> 4;
    int wstride = gridDim.x * 8;

    for (int ti = blockIdx.x * 8 + wave; ti < NTILE_E; ti += wstride) {
        int e  = ti * 16 + col;
        int s  = src[e];
        int sl = slot[e];

        f32x4 acc[8] = {};
        const float* xp = EA + (size_t)e * DIM + quad * 8;
        #pragma unroll
        for (int k0 = 0; k0 < 128; k0 += 32) {
            bf16x8 b = cvt8(xp + k0);                 // B[k][col=edge]
            #pragma unroll
            for (int t = 0; t < 8; ++t) {
                bf16x8 a = ldsA(sW, t, col, quad, k0); // A[row=dim][k]
                acc[t] = __builtin_amdgcn_mfma_f32_16x16x32_bf16(a, b, acc[t], 0, 0, 0);
            }
        }

        // gather src row from permuted bf16 Hb: 4 contiguous 16B loads
        const __hip_bfloat16* hp = Hb + (size_t)s * DIM + quad * 32;
        bf16x8 hv4[4];
        #pragma unroll
        for (int tp = 0; tp < 4; ++tp) hv4[tp] = *(const bf16x8*)(hp + tp * 8);

        __hip_bfloat16* mp = MSG + (size_t)sl * DIM + quad * 4;
        #pragma unroll
        for (int t = 0; t < 8; ++t) {
            f32x4 bv = *(const f32x4*)(bias + t * 16 + quad * 4);
            bf16x4 o;
            #pragma unroll
            for (int r = 0; r < 4; ++r) {
                float hf = __bfloat162float((__hip_bfloat16)hv4[t >> 1][(t & 1) * 4 + r]);
                float v = acc[t][r] + bv[r] + hf;
                v = v / (1.f + __expf(-v));            // SiLU
                o[r] = (__bf16)v;
            }
            *(bf16x4*)(mp + t * 16) = o;
        }
    }
}

// ---------------------------------------------------------------------------
// Fused: per-node gather of contiguous msg slots + x = silu((1+eps)h+agg)
// + node_h (in-place over H) + GraphNorm sum/sumsq accumulation.
// npb nodes per 128-thread block; batch is sorted so group runs are batched.
// ---------------------------------------------------------------------------
__global__ __launch_bounds__(128) void k_gather_stats(
    const __hip_bfloat16* __restrict__ MSG, const int* __restrict__ rowptr,
    float* __restrict__ H, const float* __restrict__ node_h,
    const float* __restrict__ epsp, const int* __restrict__ batch,
    float* __restrict__ SUMS, float* __restrict__ SQS,
    float* __restrict__ CNT, int npb)
{
    int d = threadIdx.x;
    int n0 = blockIdx.x * npb;
    int nend = min(n0 + npb, NN);
    if (n0 >= NN) return;
    float epsv = 1.f + epsp[0];
    int cur_g = batch[n0];
    float run = 0.f, run2 = 0.f; int runlen = 0;
    for (int n = n0; n < nend; ++n) {
        int g = batch[n];
        if (g != cur_g) {
            atomicAdd(&SUMS[cur_g * DIM + d], run);
            atomicAdd(&SQS[cur_g * DIM + d], run2);
            if (d == 0) atomicAdd(&CNT[cur_g], (float)runlen);
            run = 0.f; run2 = 0.f; runlen = 0; cur_g = g;
        }
        int s = rowptr[n], epos = rowptr[n + 1];
        const __hip_bfloat16* mp = MSG + (size_t)s * DIM + d;
        float a0 = 0.f, a1 = 0.f, a2 = 0.f, a3 = 0.f;
        int e = s;
        for (; e + 4 <= epos; e += 4, mp += 4 * DIM) {
            a0 += __bfloat162float(mp[0]);
            a1 += __bfloat162float(mp[DIM]);
            a2 += __bfloat162float(mp[2 * DIM]);
            a3 += __bfloat162float(mp[3 * DIM]);
        }
        for (; e < epos; ++e, mp += DIM) a0 += __bfloat162float(mp[0]);
        float agg = (a0 + a1) + (a2 + a3);
        size_t idx = (size_t)n * DIM + d;
        float v = epsv * H[idx] + agg;
        v = v / (1.f + __expf(-v));
        v += node_h[idx];
        H[idx] = v;
        run += v; run2 += v * v; runlen++;
    }
    atomicAdd(&SUMS[cur_g * DIM + d], run);
    atomicAdd(&SQS[cur_g * DIM + d], run2);
    if (d == 0) atomicAdd(&CNT[cur_g], (float)runlen);
}

// ===========================================================================
// GraphNorm finalize: var = E[x^2] - mean^2 * ms * (2 - ms).
// ===========================================================================
__global__ __launch_bounds__(128) void finalize(
    const float* __restrict__ X, const int* __restrict__ batch,
    const float* __restrict__ msc,
    const float* __restrict__ SUMS, const float* __restrict__ SQS,
    const float* __restrict__ CNT,
    const float* __restrict__ gw, const float* __restrict__ gb,
    float* __restrict__ OUT, int npb)
{
    int d = threadIdx.x;
    int n0 = blockIdx.x * npb;
    int nend = min(n0 + npb, NN);
    if (n0 >= NN) return;
    float ms = msc[d], wd = gw[d], bd = gb[d];
    int cur_g = -1;
    float mean = 0.f, rstd = 0.f;
    for (int n = n0; n < nend; ++n) {
        int g = batch[n];
        if (g != cur_g) {
            cur_g = g;
            float c = fmaxf(CNT[g], 1.f);
            mean = SUMS[g * DIM + d] / c;
            float ex2 = SQS[g * DIM + d] / c;
            float var = ex2 - mean * mean * ms * (2.f - ms);
            rstd = rsqrtf(fmaxf(var, 0.f) + 1e-5f);
        }
        size_t idx = (size_t)n * DIM + d;
        float v = X[idx] - mean * ms;
        OUT[idx] = wd * v * rstd + bd;
    }
}

// ===========================================================================
// Fallback path kernels (atomic scatter) if ws is too small
// ===========================================================================
__global__ __launch_bounds__(128) void stats_pass(
    const float* __restrict__ X, const int* __restrict__ batch,
    float* __restrict__ SUMS, float* __restrict__ SQS,
    float* __restrict__ CNT, int npb)
{
    int d = threadIdx.x;
    int n0 = blockIdx.x * npb;
    int nend = min(n0 + npb, NN);
    if (n0 >= NN) return;
    int cur_g = batch[n0];
    float run = 0.f, run2 = 0.f; int runlen = 0;
    for (int n = n0; n < nend; ++n) {
        int g = batch[n];
        if (g != cur_g) {
            atomicAdd(&SUMS[cur_g * DIM + d], run);
            atomicAdd(&SQS[cur_g * DIM + d], run2);
            if (d == 0) atomicAdd(&CNT[cur_g], (float)runlen);
            run = 0.f; run2 = 0.f; runlen = 0; cur_g = g;
        }
        float x = X[(size_t)n * DIM + d];
        run += x; run2 += x * x; runlen++;
    }
    atomicAdd(&SUMS[cur_g * DIM + d], run);
    atomicAdd(&SQS[cur_g * DIM + d], run2);
    if (d == 0) atomicAdd(&CNT[cur_g], (float)runlen);
}

__global__ __launch_bounds__(512) void edge_msg_atomic(
    const float* __restrict__ EA, const float* __restrict__ W,
    const float* __restrict__ bias,
    const int* __restrict__ src, const int* __restrict__ dst,
    const float* __restrict__ H, float* __restrict__ AGG)
{
    __shared__ __bf16 sW[128 * 128];
    int wave = threadIdx.x >> 6, lane = threadIdx.x & 63;
    int col = lane & 15, quad = lane >> 4;
    int tile = (blockIdx.x * 8 + wave) * 16;
    bool active = (tile < NE);
    int e = active ? (tile + col) : 0;
    int s = src[e], dd = dst[e];

    stage_weights_swz<512>(W, sW);
    if (!active) return;

    f32x4 acc[8] = {};
    const float* xp = EA + (size_t)e * DIM + quad * 8;
    #pragma unroll
    for (int k0 = 0; k0 < 128; k0 += 32) {
        bf16x8 b = cvt8(xp + k0);
        #pragma unroll
        for (int t = 0; t < 8; ++t) {
            bf16x8 a = ldsA(sW, t, col, quad, k0);
            acc[t] = __builtin_amdgcn_mfma_f32_16x16x32_bf16(a, b, acc[t], 0, 0, 0);
        }
    }
    const float* hp = H + (size_t)s * DIM + quad * 4;
    f32x4 hv[8];
    #pragma unroll
    for (int t = 0; t < 8; ++t) hv[t] = *(const f32x4*)(hp + t * 16);

    float* ap = AGG + (size_t)dd * DIM + quad * 4;
    #pragma unroll
    for (int t = 0; t < 8; ++t) {
        f32x4 bv = *(const f32x4*)(bias + t * 16 + quad * 4);
        #pragma unroll
        for (int r = 0; r < 4; ++r) {
            float v = acc[t][r] + bv[r] + hv[t][r];
            v = v / (1.f + __expf(-v));
            atomicAdd(&ap[t * 16 + r], v);
        }
    }
}

__global__ __launch_bounds__(128) void fuse_x_atomic(
    float* __restrict__ H, const float* __restrict__ AGG,
    const float* __restrict__ node_h, const float* __restrict__ epsp, int npb)
{
    int d = threadIdx.x;
    int n0 = blockIdx.x * npb;
    int nend = min(n0 + npb, NN);
    if (n0 >= NN) return;
    float epsv = 1.f + epsp[0];
    for (int n = n0; n < nend; ++n) {
        size_t idx = (size_t)n * DIM + d;
        float v = epsv * H[idx] + AGG[idx];
        v = v / (1.f + __expf(-v));
        H[idx] = v + node_h[idx];
    }
}

// ===========================================================================
extern "C" void kernel_launch(void* const* d_in, const int* in_sizes, int n_in,
                              void* d_out, int out_size, void* d_ws, size_t ws_size,
                              hipStream_t stream) {
    const float* node_h    = (const float*)d_in[0];
    const float* edge_attr = (const float*)d_in[1];
    const int*   batch     = (const int*)d_in[2];
    const int*   eidx      = (const int*)d_in[3];   // [2][NE]: src, dst
    const float* w1        = (const float*)d_in[4];
    const float* b1        = (const float*)d_in[5];
    const float* we        = (const float*)d_in[6];
    const float* be        = (const float*)d_in[7];
    const float* eps       = (const float*)d_in[8];
    const float* gnw       = (const float*)d_in[9];
    const float* gnb       = (const float*)d_in[10];
    const float* gnms      = (const float*)d_in[11];
    const int* src = eidx, * dst = eidx + NE;

    char* base = (char*)d_ws;
    float* H = (float*)base;                                    // 25.6 MB

    // fast-path layout (bytes)
    size_t oMSG   = 25600000;                                   // bf16 [E][128] = 153.6 MB
    size_t oROW   = oMSG + 153600000;                           // int [NN+1]
    size_t oDEG   = oROW + 200064;                              // int [NN]   (also pos)
    size_t oSUMS  = oDEG + 200000;                              // f [G*D]
    size_t oSQS   = oSUMS + 32768;                              // f [G*D]
    size_t oCNT   = oSQS + 32768;
    size_t oSLOT  = oCNT + 256;                                 // int [NE]
    size_t oCSA   = oSLOT + 2400000;                            // chunkSum int[128]
    size_t oCSB   = oCSA + 512;                                 // chunkOff int[128]
    size_t oHB    = oCSB + 512;                                 // bf16 [NN][128] = 12.8 MB
    size_t needed = oHB + 12800000;

    bool fast = ws_size >= needed;

    if (fast) {
        __hip_bfloat16* MSG = (__hip_bfloat16*)(base + oMSG);
        int* rowptr = (int*)(base + oROW);
        int* deg    = (int*)(base + oDEG);
        float* SUMS = (float*)(base + oSUMS);
        float* SQS  = (float*)(base + oSQS);
        float* CNT  = (float*)(base + oCNT);
        int* slot   = (int*)(base + oSLOT);
        int* csum   = (int*)(base + oCSA);
        int* coff   = (int*)(base + oCSB);
        __hip_bfloat16* Hb = (__hip_bfloat16*)(base + oHB);

        // zero deg + SUMS + SQS + CNT (contiguous)
        hipMemsetAsync(deg, 0, 200000 + 32768 + 32768 + 256, stream);

        gemm_bias<<<391, 512, 0, stream>>>(node_h, w1, b1, H, Hb, NN);
        k_hist  <<<(NE + 255) / 256, 256, 0, stream>>>(dst, deg);
        k_scan_a<<<NCHUNK, 256, 0, stream>>>(deg, csum);
        k_scan_b<<<1, 128, 0, stream>>>(csum, coff, rowptr);
        k_scan_c<<<NCHUNK, 512, 0, stream>>>(deg, coff, rowptr, deg /*pos, zeroed in-kernel*/);
        k_slot  <<<(NE + 255) / 256, 256, 0, stream>>>(dst, rowptr, deg, slot);
        edge_msg_sorted<<<EDGE_BLOCKS, 512, 0, stream>>>(edge_attr, we, be, src, slot, Hb, MSG);
        k_gather_stats<<<3125, 128, 0, stream>>>(MSG, rowptr, H, node_h, eps, batch,
                                                 SUMS, SQS, CNT, 16);
        finalize<<<3125, 128, 0, stream>>>(H, batch, gnms, SUMS, SQS, CNT, gnw, gnb,
                                           (float*)d_out, 16);
    } else {
        // fallback: atomic path (ws >= ~51.3 MB known to exist)
        float* AGG  = H + 6400000;
        float* SUMS = H + 12800000;
        float* SQS  = SUMS + NG * DIM;
        float* CNT  = SQS + NG * DIM;
        hipMemsetAsync(AGG, 0, (size_t)(6400000 + NG * DIM * 2 + NG) * sizeof(float), stream);
        gemm_bias<<<391, 512, 0, stream>>>(node_h, w1, b1, H, nullptr, NN);
        edge_msg_atomic<<<4688, 512, 0, stream>>>(edge_attr, we, be, src, dst, H, AGG);
        fuse_x_atomic<<<3125, 128, 0, stream>>>(H, AGG, node_h, eps, 16);
        stats_pass<<<3125, 128, 0, stream>>>(H, batch, SUMS, SQS, CNT, 16);
        finalize  <<<3125, 128, 0, stream>>>(H, batch, gnms, SUMS, SQS, CNT, gnw, gnb,
                                             (float*)d_out, 16);
    }
}